// Round 4
// baseline (6732.278 us; speedup 1.0000x reference)
//
#include <hip/hip_runtime.h>

#define HID 1024
#define AL  128
#define OPS 16
#define GS  32
#define NBLK 64          // 64 blocks x 1024 threads = 65536 lanes
#define TPB  1024

// ws layout (float offsets)
#define WS_HBUF    0         // [2 layers][2 bufs][1024]
#define WS_OUTMAIN 4096      // [128][1024]
#define WS_OUTGAP  135168    // [128][1024]
#define WS_PE      266240    // [128]
#define WS_PL      266368    // [128]
#define WS_CNT     266496    // 1 x unsigned

__device__ __forceinline__ float sig_(float x) { return 1.0f / (1.0f + expf(-x)); }

// Grid-wide barrier: 64 arrivals on one agent-scope counter.
// release (fetch_add ACQ_REL) publishes this block's h store; acquire load
// invalidates L1/L2 so post-barrier normal loads see fresh h.
__device__ __forceinline__ void gridbar(unsigned* cnt, unsigned target) {
    __syncthreads();
    if (threadIdx.x == 0) {
        __hip_atomic_fetch_add(cnt, 1u, __ATOMIC_ACQ_REL, __HIP_MEMORY_SCOPE_AGENT);
        while (__hip_atomic_load(cnt, __ATOMIC_RELAXED, __HIP_MEMORY_SCOPE_AGENT) < target)
            __builtin_amdgcn_s_sleep(1);
        (void)__hip_atomic_load(cnt, __ATOMIC_ACQUIRE, __HIP_MEMORY_SCOPE_AGENT);
    }
    __syncthreads();
}

__global__ void k_init(float* ws) {
    const int i = blockIdx.x * blockDim.x + threadIdx.x;
    if (i < 4096) ws[WS_HBUF + i] = 0.f;          // h double-buffers, both layers
    if (i == 0) *(unsigned*)(ws + WS_CNT) = 0u;   // barrier counter
}

// One LSTM layer-cell. Wave owns hidden unit u; 4 gate rows over concat([x,h])
// with weights pinned in registers; c replicated per-lane; lane 0 publishes h.
template<int LY>
__device__ __forceinline__ void cell(
    const float4 (&w)[2][4][8], const float (&bs)[2][4], float (&cst)[2],
    const float*& xsrc, float* Hbuf, int& par, unsigned& nbar, unsigned* cnt,
    int tid, int lane, int u, float* lds_cat, float* snap)
{
    {   // stage x (256 float4) and own-layer h (256 float4) into LDS: [x | h]
        float4* d = (float4*)lds_cat;
        if (tid < 256) {
            d[tid] = ((const float4*)xsrc)[tid];
        } else if (tid < 512) {
            d[tid] = ((const float4*)(Hbuf + LY * 2048 + par * 1024))[tid - 256];
        }
    }
    __syncthreads();

    float a0 = 0.f, a1 = 0.f, a2 = 0.f, a3 = 0.f;
    const float4* l4 = (const float4*)lds_cat;
#pragma unroll
    for (int k = 0; k < 8; k++) {
        float4 v = l4[lane + 64 * k];   // contiguous 1KB per instr: conflict-free
        a0 += w[LY][0][k].x * v.x + w[LY][0][k].y * v.y + w[LY][0][k].z * v.z + w[LY][0][k].w * v.w;
        a1 += w[LY][1][k].x * v.x + w[LY][1][k].y * v.y + w[LY][1][k].z * v.z + w[LY][1][k].w * v.w;
        a2 += w[LY][2][k].x * v.x + w[LY][2][k].y * v.y + w[LY][2][k].z * v.z + w[LY][2][k].w * v.w;
        a3 += w[LY][3][k].x * v.x + w[LY][3][k].y * v.y + w[LY][3][k].z * v.z + w[LY][3][k].w * v.w;
    }
#pragma unroll
    for (int off = 32; off > 0; off >>= 1) {
        a0 += __shfl_xor(a0, off, 64);
        a1 += __shfl_xor(a1, off, 64);
        a2 += __shfl_xor(a2, off, 64);
        a3 += __shfl_xor(a3, off, 64);
    }
    const float gi = sig_(a0 + bs[LY][0]);
    const float gf = sig_(a1 + bs[LY][1]);
    const float gg = tanhf(a2 + bs[LY][2]);
    const float go = sig_(a3 + bs[LY][3]);
    const float c  = gf * cst[LY] + gi * gg;
    cst[LY] = c;
    const float h = go * tanhf(c);

    par ^= 1;
    if (lane == 0) {
        // write-through (agent-scope) publish of h
        __hip_atomic_store(&Hbuf[LY * 2048 + par * 1024 + u], h,
                           __ATOMIC_RELAXED, __HIP_MEMORY_SCOPE_AGENT);
        if (snap) snap[u] = h;
    }
    ++nbar;
    gridbar(cnt, nbar * (unsigned)NBLK);
    xsrc = Hbuf + LY * 2048 + par * 1024;
}

__global__ __launch_bounds__(TPB, 1) void k_chain(
    const float* __restrict__ g_emb, const float* __restrict__ W_ih,
    const float* __restrict__ W_hh, const float* __restrict__ b_ih,
    const float* __restrict__ b_hh, const int* __restrict__ config, float* ws)
{
    const int tid  = threadIdx.x;
    const int bid  = blockIdx.x;
    const int lane = tid & 63;
    const int u    = bid * 16 + (tid >> 6);   // hidden unit owned by this wave

    float* Hbuf    = ws + WS_HBUF;
    float* OutMain = ws + WS_OUTMAIN;
    float* OutGap  = ws + WS_OUTGAP;
    unsigned* cnt  = (unsigned*)(ws + WS_CNT);

    __shared__ float lds_cat[2048];
    __shared__ int   cfg_s[AL];

    // persist weights in registers: 256 fp32/lane, pinned by opaque asm so the
    // compiler can neither rematerialize the (invariant) loads nor sink them.
    float4 w[2][4][8];
    float  bs[2][4];
#pragma unroll
    for (int l = 0; l < 2; l++) {
#pragma unroll
        for (int r = 0; r < 4; r++) {
            const float* Wi = W_ih + (size_t)l * 4 * HID * HID + (size_t)(r * HID + u) * HID;
            const float* Wh = W_hh + (size_t)l * 4 * HID * HID + (size_t)(r * HID + u) * HID;
#pragma unroll
            for (int k = 0; k < 4; k++) w[l][r][k]     = *(const float4*)(Wi + 4 * lane + 256 * k);
#pragma unroll
            for (int k = 0; k < 4; k++) w[l][r][4 + k] = *(const float4*)(Wh + 4 * lane + 256 * k);
            bs[l][r] = b_ih[l * 4 * HID + r * HID + u] + b_hh[l * 4 * HID + r * HID + u];
#pragma unroll
            for (int k = 0; k < 8; k++) {
                asm volatile("" : "+v"(w[l][r][k].x), "+v"(w[l][r][k].y),
                                  "+v"(w[l][r][k].z), "+v"(w[l][r][k].w));
            }
        }
    }
    if (tid < AL) cfg_s[tid] = config[tid];
    __syncthreads();

    float cst[2] = {0.f, 0.f};
    int par0 = 0, par1 = 0;
    unsigned nbar = 0;
    const float* xsrc = g_emb;

    for (int t = 0; t < AL; t++) {
        cell<0>(w, bs, cst, xsrc, Hbuf, par0, nbar, cnt, tid, lane, u, lds_cat, nullptr);
        cell<1>(w, bs, cst, xsrc, Hbuf, par1, nbar, cnt, tid, lane, u, lds_cat, OutMain + t * HID);
        if (cfg_s[t] == 1) {   // gap pass only matters when cfg == 1
            cell<0>(w, bs, cst, xsrc, Hbuf, par0, nbar, cnt, tid, lane, u, lds_cat, nullptr);
            cell<1>(w, bs, cst, xsrc, Hbuf, par1, nbar, cnt, tid, lane, u, lds_cat, OutGap + t * HID);
        }
    }
}

__global__ void k_heads(
    const float* __restrict__ ctx_W, const float* __restrict__ ctx_b,
    const float* __restrict__ left_W, const float* __restrict__ left_b,
    const int* __restrict__ config, const int* __restrict__ left_config, float* ws)
{
    const int t   = blockIdx.x;    // 128 blocks, one per step
    const int tid = threadIdx.x;   // 256 threads
    const float* o1 = ws + WS_OUTMAIN + (size_t)t * HID;
    const float* o2 = ws + WS_OUTGAP  + (size_t)t * HID;
    const int cfg = config[t];

    __shared__ float lgm[OPS];
    __shared__ float lgg[GS];

    float ent = 0.f, lp = 0.f;
    {   // main head: 16 rows, 16 threads/row
        const int g = tid >> 4, l16 = tid & 15;
        const float* wr = ctx_W + ((size_t)t * OPS + g) * HID;
        float a = 0.f;
#pragma unroll 4
        for (int k = 0; k < 16; k++) {
            float4 wv = *(const float4*)(wr + 4 * l16 + 64 * k);
            float4 xv = *(const float4*)(o1 + 4 * l16 + 64 * k);
            a += wv.x * xv.x + wv.y * xv.y + wv.z * xv.z + wv.w * xv.w;
        }
#pragma unroll
        for (int off = 1; off < 16; off <<= 1) a += __shfl_xor(a, off, 64);
        if (l16 == 0) lgm[g] = a + ctx_b[t * OPS + g];
    }
    __syncthreads();
    if (tid == 0) {
        float m = -1e30f;
        for (int g = 0; g < OPS; g++) m = fmaxf(m, lgm[g]);
        float s = 0.f;
        for (int g = 0; g < OPS; g++) s += expf(lgm[g] - m);
        const float lse = m + logf(s);
        for (int g = 0; g < OPS; g++) { float ls = lgm[g] - lse; ent -= expf(ls) * ls; }
        lp += lgm[cfg] - lse;
    }
    if (cfg == 1) {   // gap head: 32 rows, 8 threads/row
        const int g = tid >> 3, l8 = tid & 7;
        const float* wr = left_W + ((size_t)t * GS + g) * HID;
        float a = 0.f;
#pragma unroll 4
        for (int k = 0; k < 32; k++) {
            float4 wv = *(const float4*)(wr + 4 * l8 + 32 * k);
            float4 xv = *(const float4*)(o2 + 4 * l8 + 32 * k);
            a += wv.x * xv.x + wv.y * xv.y + wv.z * xv.z + wv.w * xv.w;
        }
#pragma unroll
        for (int off = 1; off < 8; off <<= 1) a += __shfl_xor(a, off, 64);
        if (l8 == 0) lgg[g] = a + left_b[t * GS + g];
        __syncthreads();
        if (tid == 0) {
            float m = -1e30f;
            for (int g = 0; g < GS; g++) m = fmaxf(m, lgg[g]);
            float s = 0.f;
            for (int g = 0; g < GS; g++) s += expf(lgg[g] - m);
            const float lse = m + logf(s);
            for (int g = 0; g < GS; g++) { float ls = lgg[g] - lse; ent -= expf(ls) * ls; }
            lp += lgg[left_config[t]] - lse;
        }
    }
    if (tid == 0) { ws[WS_PE + t] = ent; ws[WS_PL + t] = lp; }
}

__global__ void k_reduce(const float* __restrict__ ws, float* __restrict__ out) {
    const int tid = threadIdx.x;   // 128 threads, 2 waves
    __shared__ float s4[4];
    float e = ws[WS_PE + tid], p = ws[WS_PL + tid];
#pragma unroll
    for (int off = 32; off > 0; off >>= 1) {
        e += __shfl_xor(e, off, 64);
        p += __shfl_xor(p, off, 64);
    }
    if ((tid & 63) == 0) { s4[(tid >> 6) * 2] = e; s4[(tid >> 6) * 2 + 1] = p; }
    __syncthreads();
    if (tid == 0) { out[0] = s4[0] + s4[2]; out[1] = s4[1] + s4[3]; }
}

extern "C" void kernel_launch(void* const* d_in, const int* in_sizes, int n_in,
                              void* d_out, int out_size, void* d_ws, size_t ws_size,
                              hipStream_t stream)
{
    const float* g_emb  = (const float*)d_in[0];
    const float* W_ih   = (const float*)d_in[1];
    const float* W_hh   = (const float*)d_in[2];
    const float* b_ih   = (const float*)d_in[3];
    const float* b_hh   = (const float*)d_in[4];
    const float* ctx_W  = (const float*)d_in[5];
    const float* ctx_b  = (const float*)d_in[6];
    const float* left_W = (const float*)d_in[7];
    const float* left_b = (const float*)d_in[8];
    const int* config      = (const int*)d_in[9];
    const int* left_config = (const int*)d_in[10];
    float* out = (float*)d_out;
    float* ws  = (float*)d_ws;

    k_init<<<dim3(16), dim3(256), 0, stream>>>(ws);
    k_chain<<<dim3(NBLK), dim3(TPB), 0, stream>>>(g_emb, W_ih, W_hh, b_ih, b_hh, config, ws);
    k_heads<<<dim3(AL), dim3(256), 0, stream>>>(ctx_W, ctx_b, left_W, left_b,
                                                config, left_config, ws);
    k_reduce<<<dim3(1), dim3(128), 0, stream>>>(ws, out);
}

// Round 5
// 3058.980 us; speedup vs baseline: 2.2008x; 2.2008x over previous
//
#include <hip/hip_runtime.h>

#define HID 1024
#define AL  128
#define OPS 16
#define GS  32
#define NBLK 256
#define TPB  256

// ws layout (float offsets)
#define WS_HBUF    0         // [2 layers][2 bufs][1024]
#define WS_OUTMAIN 4096      // [128][1024]
#define WS_OUTGAP  135168    // [128][1024]
#define WS_PE      266240    // [128]
#define WS_PL      266368    // [128]
#define WS_CNT     266496    // barrier counters: 16 group ctrs @ 128B stride, root @ +512 uints

__device__ __forceinline__ float sig_(float x) { return 1.0f / (1.0f + expf(-x)); }

// Two-level grid barrier: 16 groups x 16 blocks. Group counters live on
// separate 128B lines; last arriver of each group bumps the root. The
// ACQ_REL RMW chain (arrival -> group -> root) transitively publishes every
// block's pre-barrier stores to every block that acquires the root.
__device__ __forceinline__ void gridbar(unsigned* cnt, int bid, unsigned nbar) {
    __syncthreads();
    if (threadIdx.x == 0) {
        unsigned* grp  = cnt + ((unsigned)bid >> 4) * 32u;  // 16 groups, 128B apart
        unsigned* root = cnt + 512u;
        unsigned old = __hip_atomic_fetch_add(grp, 1u, __ATOMIC_ACQ_REL, __HIP_MEMORY_SCOPE_AGENT);
        if (old == nbar * 16u - 1u)   // last of my group this epoch
            __hip_atomic_fetch_add(root, 1u, __ATOMIC_ACQ_REL, __HIP_MEMORY_SCOPE_AGENT);
        while (__hip_atomic_load(root, __ATOMIC_RELAXED, __HIP_MEMORY_SCOPE_AGENT) < nbar * 16u)
            __builtin_amdgcn_s_sleep(1);
        (void)__hip_atomic_load(root, __ATOMIC_ACQUIRE, __HIP_MEMORY_SCOPE_AGENT);
    }
    __syncthreads();
}

__global__ void k_init(float* ws) {
    const int i = blockIdx.x * blockDim.x + threadIdx.x;
    if (i < 4096) ws[WS_HBUF + i] = 0.f;                     // h double-buffers
    if (i < 1024) ((unsigned*)(ws + WS_CNT))[i] = 0u;        // all barrier counters
}

#define WIDX(l, r, k, c) ((((l) * 4 + (r)) * 8 + (k)) * 4 + (c))

// One LSTM layer-cell. Wave owns hidden unit u; 4 gate rows over concat([x,h])
// with weights resident in AGPRs; c replicated per-lane; lane 0 publishes h.
template<int LY>
__device__ __forceinline__ void cell(
    float (&wa)[256], const float (&bs)[2][4], float (&cst)[2],
    const float*& xsrc, float* Hbuf, int& par, unsigned& nbar, unsigned* cnt,
    int tid, int bid, int lane, int u, float* lds_cat, float* snap)
{
    {   // stage x (256 float4) and own-layer h (256 float4) into LDS: [x | h]
        const float4* xs = (const float4*)xsrc;
        const float4* hs = (const float4*)(Hbuf + LY * 2048 + par * 1024);
        float4* d = (float4*)lds_cat;
        d[tid]       = xs[tid];
        d[256 + tid] = hs[tid];
    }
    __syncthreads();

    float acc[4] = {0.f, 0.f, 0.f, 0.f};
    const float4* l4 = (const float4*)lds_cat;
#pragma unroll
    for (int k = 0; k < 8; k++) {
        float4 v = l4[lane + 64 * k];   // contiguous 1KB per instr: conflict-free
#pragma unroll
        for (int r = 0; r < 4; r++) {
            float w0, w1, w2, w3;
            asm volatile("v_accvgpr_read_b32 %0, %1" : "=v"(w0) : "a"(wa[WIDX(LY, r, k, 0)]));
            asm volatile("v_accvgpr_read_b32 %0, %1" : "=v"(w1) : "a"(wa[WIDX(LY, r, k, 1)]));
            asm volatile("v_accvgpr_read_b32 %0, %1" : "=v"(w2) : "a"(wa[WIDX(LY, r, k, 2)]));
            asm volatile("v_accvgpr_read_b32 %0, %1" : "=v"(w3) : "a"(wa[WIDX(LY, r, k, 3)]));
            acc[r] += w0 * v.x + w1 * v.y + w2 * v.z + w3 * v.w;
        }
    }
#pragma unroll
    for (int off = 32; off > 0; off >>= 1) {
        acc[0] += __shfl_xor(acc[0], off, 64);
        acc[1] += __shfl_xor(acc[1], off, 64);
        acc[2] += __shfl_xor(acc[2], off, 64);
        acc[3] += __shfl_xor(acc[3], off, 64);
    }
    const float gi = sig_(acc[0] + bs[LY][0]);
    const float gf = sig_(acc[1] + bs[LY][1]);
    const float gg = tanhf(acc[2] + bs[LY][2]);
    const float go = sig_(acc[3] + bs[LY][3]);
    const float c  = gf * cst[LY] + gi * gg;
    cst[LY] = c;
    const float h = go * tanhf(c);

    par ^= 1;
    if (lane == 0) {
        // write-through (agent-scope) publish of h
        __hip_atomic_store(&Hbuf[LY * 2048 + par * 1024 + u], h,
                           __ATOMIC_RELAXED, __HIP_MEMORY_SCOPE_AGENT);
        if (snap) snap[u] = h;
    }
    ++nbar;
    gridbar(cnt, bid, nbar);
    xsrc = Hbuf + LY * 2048 + par * 1024;
}

__global__ __launch_bounds__(TPB, 1) void k_chain(
    const float* __restrict__ g_emb, const float* __restrict__ W_ih,
    const float* __restrict__ W_hh, const float* __restrict__ b_ih,
    const float* __restrict__ b_hh, const int* __restrict__ config, float* ws)
{
    const int tid  = threadIdx.x;
    const int bid  = blockIdx.x;
    const int lane = tid & 63;
    const int u    = bid * 4 + (tid >> 6);   // hidden unit owned by this wave

    float* Hbuf    = ws + WS_HBUF;
    float* OutMain = ws + WS_OUTMAIN;
    float* OutGap  = ws + WS_OUTGAP;
    unsigned* cnt  = (unsigned*)(ws + WS_CNT);

    __shared__ float lds_cat[2048];
    __shared__ int   cfg_s[AL];

    // Persist weights in AGPRs: 256 fp32/lane moved into the accumulator half
    // of the unified register file via explicit v_accvgpr_write. Exactly 256
    // "a"-class values -> feasible allocation, no scratch.
    float wa[256];
    float bs[2][4];
#pragma unroll
    for (int l = 0; l < 2; l++) {
#pragma unroll
        for (int r = 0; r < 4; r++) {
            const float* Wi = W_ih + (size_t)l * 4 * HID * HID + (size_t)(r * HID + u) * HID;
            const float* Wh = W_hh + (size_t)l * 4 * HID * HID + (size_t)(r * HID + u) * HID;
#pragma unroll
            for (int k = 0; k < 4; k++) {
                float4 t = *(const float4*)(Wi + 4 * lane + 256 * k);
                asm volatile("v_accvgpr_write_b32 %0, %1" : "=a"(wa[WIDX(l, r, k, 0)]) : "v"(t.x));
                asm volatile("v_accvgpr_write_b32 %0, %1" : "=a"(wa[WIDX(l, r, k, 1)]) : "v"(t.y));
                asm volatile("v_accvgpr_write_b32 %0, %1" : "=a"(wa[WIDX(l, r, k, 2)]) : "v"(t.z));
                asm volatile("v_accvgpr_write_b32 %0, %1" : "=a"(wa[WIDX(l, r, k, 3)]) : "v"(t.w));
            }
#pragma unroll
            for (int k = 0; k < 4; k++) {
                float4 t = *(const float4*)(Wh + 4 * lane + 256 * k);
                asm volatile("v_accvgpr_write_b32 %0, %1" : "=a"(wa[WIDX(l, r, k + 4, 0)]) : "v"(t.x));
                asm volatile("v_accvgpr_write_b32 %0, %1" : "=a"(wa[WIDX(l, r, k + 4, 1)]) : "v"(t.y));
                asm volatile("v_accvgpr_write_b32 %0, %1" : "=a"(wa[WIDX(l, r, k + 4, 2)]) : "v"(t.z));
                asm volatile("v_accvgpr_write_b32 %0, %1" : "=a"(wa[WIDX(l, r, k + 4, 3)]) : "v"(t.w));
            }
            bs[l][r] = b_ih[l * 4 * HID + r * HID + u] + b_hh[l * 4 * HID + r * HID + u];
        }
    }
    if (tid < AL) cfg_s[tid] = config[tid];
    __syncthreads();

    float cst[2] = {0.f, 0.f};
    int par0 = 0, par1 = 0;
    unsigned nbar = 0;
    const float* xsrc = g_emb;

    for (int t = 0; t < AL; t++) {
        cell<0>(wa, bs, cst, xsrc, Hbuf, par0, nbar, cnt, tid, bid, lane, u, lds_cat, nullptr);
        cell<1>(wa, bs, cst, xsrc, Hbuf, par1, nbar, cnt, tid, bid, lane, u, lds_cat, OutMain + t * HID);
        if (cfg_s[t] == 1) {   // gap pass only matters when cfg == 1
            cell<0>(wa, bs, cst, xsrc, Hbuf, par0, nbar, cnt, tid, bid, lane, u, lds_cat, nullptr);
            cell<1>(wa, bs, cst, xsrc, Hbuf, par1, nbar, cnt, tid, bid, lane, u, lds_cat, OutGap + t * HID);
        }
    }
}

__global__ void k_heads(
    const float* __restrict__ ctx_W, const float* __restrict__ ctx_b,
    const float* __restrict__ left_W, const float* __restrict__ left_b,
    const int* __restrict__ config, const int* __restrict__ left_config, float* ws)
{
    const int t   = blockIdx.x;    // 128 blocks, one per step
    const int tid = threadIdx.x;   // 256 threads
    const float* o1 = ws + WS_OUTMAIN + (size_t)t * HID;
    const float* o2 = ws + WS_OUTGAP  + (size_t)t * HID;
    const int cfg = config[t];

    __shared__ float lgm[OPS];
    __shared__ float lgg[GS];

    float ent = 0.f, lp = 0.f;
    {   // main head: 16 rows, 16 threads/row
        const int g = tid >> 4, l16 = tid & 15;
        const float* wr = ctx_W + ((size_t)t * OPS + g) * HID;
        float a = 0.f;
#pragma unroll 4
        for (int k = 0; k < 16; k++) {
            float4 wv = *(const float4*)(wr + 4 * l16 + 64 * k);
            float4 xv = *(const float4*)(o1 + 4 * l16 + 64 * k);
            a += wv.x * xv.x + wv.y * xv.y + wv.z * xv.z + wv.w * xv.w;
        }
#pragma unroll
        for (int off = 1; off < 16; off <<= 1) a += __shfl_xor(a, off, 64);
        if (l16 == 0) lgm[g] = a + ctx_b[t * OPS + g];
    }
    __syncthreads();
    if (tid == 0) {
        float m = -1e30f;
        for (int g = 0; g < OPS; g++) m = fmaxf(m, lgm[g]);
        float s = 0.f;
        for (int g = 0; g < OPS; g++) s += expf(lgm[g] - m);
        const float lse = m + logf(s);
        for (int g = 0; g < OPS; g++) { float ls = lgm[g] - lse; ent -= expf(ls) * ls; }
        lp += lgm[cfg] - lse;
    }
    if (cfg == 1) {   // gap head: 32 rows, 8 threads/row
        const int g = tid >> 3, l8 = tid & 7;
        const float* wr = left_W + ((size_t)t * GS + g) * HID;
        float a = 0.f;
#pragma unroll 4
        for (int k = 0; k < 32; k++) {
            float4 wv = *(const float4*)(wr + 4 * l8 + 32 * k);
            float4 xv = *(const float4*)(o2 + 4 * l8 + 32 * k);
            a += wv.x * xv.x + wv.y * xv.y + wv.z * xv.z + wv.w * xv.w;
        }
#pragma unroll
        for (int off = 1; off < 8; off <<= 1) a += __shfl_xor(a, off, 64);
        if (l8 == 0) lgg[g] = a + left_b[t * GS + g];
        __syncthreads();
        if (tid == 0) {
            float m = -1e30f;
            for (int g = 0; g < GS; g++) m = fmaxf(m, lgg[g]);
            float s = 0.f;
            for (int g = 0; g < GS; g++) s += expf(lgg[g] - m);
            const float lse = m + logf(s);
            for (int g = 0; g < GS; g++) { float ls = lgg[g] - lse; ent -= expf(ls) * ls; }
            lp += lgg[left_config[t]] - lse;
        }
    }
    if (tid == 0) { ws[WS_PE + t] = ent; ws[WS_PL + t] = lp; }
}

__global__ void k_reduce(const float* __restrict__ ws, float* __restrict__ out) {
    const int tid = threadIdx.x;   // 128 threads, 2 waves
    __shared__ float s4[4];
    float e = ws[WS_PE + tid], p = ws[WS_PL + tid];
#pragma unroll
    for (int off = 32; off > 0; off >>= 1) {
        e += __shfl_xor(e, off, 64);
        p += __shfl_xor(p, off, 64);
    }
    if ((tid & 63) == 0) { s4[(tid >> 6) * 2] = e; s4[(tid >> 6) * 2 + 1] = p; }
    __syncthreads();
    if (tid == 0) { out[0] = s4[0] + s4[2]; out[1] = s4[1] + s4[3]; }
}

extern "C" void kernel_launch(void* const* d_in, const int* in_sizes, int n_in,
                              void* d_out, int out_size, void* d_ws, size_t ws_size,
                              hipStream_t stream)
{
    const float* g_emb  = (const float*)d_in[0];
    const float* W_ih   = (const float*)d_in[1];
    const float* W_hh   = (const float*)d_in[2];
    const float* b_ih   = (const float*)d_in[3];
    const float* b_hh   = (const float*)d_in[4];
    const float* ctx_W  = (const float*)d_in[5];
    const float* ctx_b  = (const float*)d_in[6];
    const float* left_W = (const float*)d_in[7];
    const float* left_b = (const float*)d_in[8];
    const int* config      = (const int*)d_in[9];
    const int* left_config = (const int*)d_in[10];
    float* out = (float*)d_out;
    float* ws  = (float*)d_ws;

    k_init<<<dim3(16), dim3(256), 0, stream>>>(ws);
    k_chain<<<dim3(NBLK), dim3(TPB), 0, stream>>>(g_emb, W_ih, W_hh, b_ih, b_hh, config, ws);
    k_heads<<<dim3(AL), dim3(256), 0, stream>>>(ctx_W, ctx_b, left_W, left_b,
                                                config, left_config, ws);
    k_reduce<<<dim3(1), dim3(128), 0, stream>>>(ws, out);
}

// Round 7
// 1776.812 us; speedup vs baseline: 3.7890x; 1.7216x over previous
//
#include <hip/hip_runtime.h>

#define HID 1024
#define AL  128
#define OPS 16
#define GS  32
#define NBLK 256
#define TPB  256

// ws layout (float offsets)
#define WS_HBUF    0         // [2 layers][2 bufs][1024]
#define WS_OUTMAIN 4096      // [128][1024]
#define WS_OUTGAP  135168    // [128][1024]
#define WS_PE      266240    // [128]
#define WS_PL      266368    // [128]
#define WS_CNT     266496    // barrier counters: 16 group ctrs @128B stride, root @ +512 uints

__device__ __forceinline__ float sig_(float x) { return 1.0f / (1.0f + expf(-x)); }

// Coherence-point (L3) access helpers: sc0 sc1 bypass L1 + non-coherent L2.
__device__ __forceinline__ void st_coh(float* p, float v) {
    asm volatile("global_store_dword %0, %1, off sc0 sc1" :: "v"(p), "v"(v) : "memory");
}
__device__ __forceinline__ void ld_coh_issue(float4& dst, const float4* p) {
    asm volatile("global_load_dwordx4 %0, %1, off sc0 sc1" : "=v"(dst) : "v"(p) : "memory");
}
// Drain outstanding vm ops; sched_barrier stops the compiler from hoisting
// dependent uses above the wait (rule #18).
__device__ __forceinline__ void wait_vm0() {
    asm volatile("s_waitcnt vmcnt(0)" ::: "memory");
    __builtin_amdgcn_sched_barrier(0);
}

__global__ void k_init(float* ws) {
    const int i = blockIdx.x * blockDim.x + threadIdx.x;
    if (i < 4096) ws[WS_HBUF + i] = 0.f;                     // h double-buffers
    if (i < 1024) ((unsigned*)(ws + WS_CNT))[i] = 0u;        // all barrier counters
}

#define WIDX(l, r, k, c) ((((l) * 4 + (r)) * 8 + (k)) * 4 + (c))

// One LSTM layer-cell, fence-free protocol:
//  stage x (fresh L3 read) + h (prefetched by previous cell) -> LDS -> dot with
//  AGPR-resident weights -> butterfly -> gates -> publish h (sc0 sc1 write-through)
//  -> waitcnt -> tree-barrier arrive (relaxed) -> prefetch next cell's recurrent h
//  -> tree-barrier wait (relaxed spin) -> done.
template<int LY>
__device__ __forceinline__ void cell(
    float (&wa)[256], const float (&bs)[2][4], float (&cst)[2],
    const float*& xsrc, float* Hbuf, int& par, int otherPar,
    unsigned& nbar, unsigned* cnt,
    int tid, int bid, int lane, int u, float* lds_cat, float* snap,
    float4& vh_pre)
{
    // ---- stage: x fresh from L3, h from prefetch ----
    float4 vx;
    ld_coh_issue(vx, (const float4*)xsrc + tid);
    wait_vm0();                      // vx and vh_pre both resident now
    {
        float4* d = (float4*)lds_cat;
        d[tid]       = vx;
        d[256 + tid] = vh_pre;
    }
    __syncthreads();

    // ---- dot: 4 gate rows, weights from AGPRs ----
    float acc[4] = {0.f, 0.f, 0.f, 0.f};
    const float4* l4 = (const float4*)lds_cat;
#pragma unroll
    for (int k = 0; k < 8; k++) {
        float4 v = l4[lane + 64 * k];   // contiguous 1KB per instr: conflict-free
#pragma unroll
        for (int r = 0; r < 4; r++) {
            float w0, w1, w2, w3;
            asm volatile("v_accvgpr_read_b32 %0, %1" : "=v"(w0) : "a"(wa[WIDX(LY, r, k, 0)]));
            asm volatile("v_accvgpr_read_b32 %0, %1" : "=v"(w1) : "a"(wa[WIDX(LY, r, k, 1)]));
            asm volatile("v_accvgpr_read_b32 %0, %1" : "=v"(w2) : "a"(wa[WIDX(LY, r, k, 2)]));
            asm volatile("v_accvgpr_read_b32 %0, %1" : "=v"(w3) : "a"(wa[WIDX(LY, r, k, 3)]));
            acc[r] += w0 * v.x + w1 * v.y + w2 * v.z + w3 * v.w;
        }
    }
#pragma unroll
    for (int off = 32; off > 0; off >>= 1) {
        acc[0] += __shfl_xor(acc[0], off, 64);
        acc[1] += __shfl_xor(acc[1], off, 64);
        acc[2] += __shfl_xor(acc[2], off, 64);
        acc[3] += __shfl_xor(acc[3], off, 64);
    }
    const float gi = sig_(acc[0] + bs[LY][0]);
    const float gf = sig_(acc[1] + bs[LY][1]);
    const float gg = tanhf(acc[2] + bs[LY][2]);
    const float go = sig_(acc[3] + bs[LY][3]);
    const float c  = gf * cst[LY] + gi * gg;
    cst[LY] = c;
    const float h = go * tanhf(c);

    // ---- publish ----
    par ^= 1;
    if (lane == 0) {
        st_coh(&Hbuf[LY * 2048 + par * 1024 + u], h);   // write-through to L3
        if (snap) snap[u] = h;                           // plain; read by next kernel
    }
    asm volatile("s_waitcnt vmcnt(0)" ::: "memory");     // per-wave: h-store at L3
    ++nbar;

    // ---- barrier arrive (relaxed tree) ----
    __syncthreads();                                     // all 4 waves' stores done
    if (tid == 0) {
        unsigned* grp  = cnt + ((unsigned)bid >> 4) * 32u;
        unsigned* root = cnt + 512u;
        unsigned old = __hip_atomic_fetch_add(grp, 1u, __ATOMIC_RELAXED, __HIP_MEMORY_SCOPE_AGENT);
        if (old == nbar * 16u - 1u)
            __hip_atomic_fetch_add(root, 1u, __ATOMIC_RELAXED, __HIP_MEMORY_SCOPE_AGENT);
    }
    // ---- prefetch next cell's recurrent h (published >=1 barrier ago; overlaps spin) ----
    {
        const float4* hnext = (const float4*)(Hbuf + (1 - LY) * 2048 + otherPar * 1024);
        ld_coh_issue(vh_pre, hnext + tid);
    }
    // ---- barrier wait ----
    if (tid == 0) {
        unsigned* root = cnt + 512u;
        while (__hip_atomic_load(root, __ATOMIC_RELAXED, __HIP_MEMORY_SCOPE_AGENT) < nbar * 16u)
            __builtin_amdgcn_s_sleep(1);
    }
    __syncthreads();
    xsrc = Hbuf + LY * 2048 + par * 1024;
}

__global__ __launch_bounds__(TPB, 1) void k_chain(
    const float* __restrict__ g_emb, const float* __restrict__ W_ih,
    const float* __restrict__ W_hh, const float* __restrict__ b_ih,
    const float* __restrict__ b_hh, const int* __restrict__ config, float* ws)
{
    const int tid  = threadIdx.x;
    const int bid  = blockIdx.x;
    const int lane = tid & 63;
    const int u    = bid * 4 + (tid >> 6);   // hidden unit owned by this wave

    float* Hbuf    = ws + WS_HBUF;
    float* OutMain = ws + WS_OUTMAIN;
    float* OutGap  = ws + WS_OUTGAP;
    unsigned* cnt  = (unsigned*)(ws + WS_CNT);

    __shared__ float lds_cat[2048];
    __shared__ int   cfg_s[AL];

    // Persist weights in AGPRs: 256 fp32/lane (1 wave/SIMD -> 512-reg budget).
    float wa[256];
    float bs[2][4];
#pragma unroll
    for (int l = 0; l < 2; l++) {
#pragma unroll
        for (int r = 0; r < 4; r++) {
            const float* Wi = W_ih + (size_t)l * 4 * HID * HID + (size_t)(r * HID + u) * HID;
            const float* Wh = W_hh + (size_t)l * 4 * HID * HID + (size_t)(r * HID + u) * HID;
#pragma unroll
            for (int k = 0; k < 4; k++) {
                float4 t = *(const float4*)(Wi + 4 * lane + 256 * k);
                asm volatile("v_accvgpr_write_b32 %0, %1" : "=a"(wa[WIDX(l, r, k, 0)]) : "v"(t.x));
                asm volatile("v_accvgpr_write_b32 %0, %1" : "=a"(wa[WIDX(l, r, k, 1)]) : "v"(t.y));
                asm volatile("v_accvgpr_write_b32 %0, %1" : "=a"(wa[WIDX(l, r, k, 2)]) : "v"(t.z));
                asm volatile("v_accvgpr_write_b32 %0, %1" : "=a"(wa[WIDX(l, r, k, 3)]) : "v"(t.w));
            }
#pragma unroll
            for (int k = 0; k < 4; k++) {
                float4 t = *(const float4*)(Wh + 4 * lane + 256 * k);
                asm volatile("v_accvgpr_write_b32 %0, %1" : "=a"(wa[WIDX(l, r, k + 4, 0)]) : "v"(t.x));
                asm volatile("v_accvgpr_write_b32 %0, %1" : "=a"(wa[WIDX(l, r, k + 4, 1)]) : "v"(t.y));
                asm volatile("v_accvgpr_write_b32 %0, %1" : "=a"(wa[WIDX(l, r, k + 4, 2)]) : "v"(t.z));
                asm volatile("v_accvgpr_write_b32 %0, %1" : "=a"(wa[WIDX(l, r, k + 4, 3)]) : "v"(t.w));
            }
            bs[l][r] = b_ih[l * 4 * HID + r * HID + u] + b_hh[l * 4 * HID + r * HID + u];
        }
    }
    if (tid < AL) cfg_s[tid] = config[tid];
    __syncthreads();

    float cst[2] = {0.f, 0.f};
    int par0 = 0, par1 = 0;
    unsigned nbar = 0;
    const float* xsrc = g_emb;
    float4 vh_pre = make_float4(0.f, 0.f, 0.f, 0.f);   // first cell's h0 = zeros

    for (int t = 0; t < AL; t++) {
        cell<0>(wa, bs, cst, xsrc, Hbuf, par0, par1, nbar, cnt, tid, bid, lane, u,
                lds_cat, nullptr, vh_pre);
        cell<1>(wa, bs, cst, xsrc, Hbuf, par1, par0, nbar, cnt, tid, bid, lane, u,
                lds_cat, OutMain + t * HID, vh_pre);
        if (cfg_s[t] == 1) {   // gap pass only matters when cfg == 1
            cell<0>(wa, bs, cst, xsrc, Hbuf, par0, par1, nbar, cnt, tid, bid, lane, u,
                    lds_cat, nullptr, vh_pre);
            cell<1>(wa, bs, cst, xsrc, Hbuf, par1, par0, nbar, cnt, tid, bid, lane, u,
                    lds_cat, OutGap + t * HID, vh_pre);
        }
    }
}

__global__ void k_heads(
    const float* __restrict__ ctx_W, const float* __restrict__ ctx_b,
    const float* __restrict__ left_W, const float* __restrict__ left_b,
    const int* __restrict__ config, const int* __restrict__ left_config, float* ws)
{
    const int t   = blockIdx.x;    // 128 blocks, one per step
    const int tid = threadIdx.x;   // 256 threads
    const float* o1 = ws + WS_OUTMAIN + (size_t)t * HID;
    const float* o2 = ws + WS_OUTGAP  + (size_t)t * HID;
    const int cfg = config[t];

    __shared__ float lgm[OPS];
    __shared__ float lgg[GS];

    float ent = 0.f, lp = 0.f;
    {   // main head: 16 rows, 16 threads/row
        const int g = tid >> 4, l16 = tid & 15;
        const float* wr = ctx_W + ((size_t)t * OPS + g) * HID;
        float a = 0.f;
#pragma unroll 4
        for (int k = 0; k < 16; k++) {
            float4 wv = *(const float4*)(wr + 4 * l16 + 64 * k);
            float4 xv = *(const float4*)(o1 + 4 * l16 + 64 * k);
            a += wv.x * xv.x + wv.y * xv.y + wv.z * xv.z + wv.w * xv.w;
        }
#pragma unroll
        for (int off = 1; off < 16; off <<= 1) a += __shfl_xor(a, off, 64);
        if (l16 == 0) lgm[g] = a + ctx_b[t * OPS + g];
    }
    __syncthreads();
    if (tid == 0) {
        float m = -1e30f;
        for (int g = 0; g < OPS; g++) m = fmaxf(m, lgm[g]);
        float s = 0.f;
        for (int g = 0; g < OPS; g++) s += expf(lgm[g] - m);
        const float lse = m + logf(s);
        for (int g = 0; g < OPS; g++) { float ls = lgm[g] - lse; ent -= expf(ls) * ls; }
        lp += lgm[cfg] - lse;
    }
    if (cfg == 1) {   // gap head: 32 rows, 8 threads/row
        const int g = tid >> 3, l8 = tid & 7;
        const float* wr = left_W + ((size_t)t * GS + g) * HID;
        float a = 0.f;
#pragma unroll 4
        for (int k = 0; k < 32; k++) {
            float4 wv = *(const float4*)(wr + 4 * l8 + 32 * k);
            float4 xv = *(const float4*)(o2 + 4 * l8 + 32 * k);
            a += wv.x * xv.x + wv.y * xv.y + wv.z * xv.z + wv.w * xv.w;
        }
#pragma unroll
        for (int off = 1; off < 8; off <<= 1) a += __shfl_xor(a, off, 64);
        if (l8 == 0) lgg[g] = a + left_b[t * GS + g];
        __syncthreads();
        if (tid == 0) {
            float m = -1e30f;
            for (int g = 0; g < GS; g++) m = fmaxf(m, lgg[g]);
            float s = 0.f;
            for (int g = 0; g < GS; g++) s += expf(lgg[g] - m);
            const float lse = m + logf(s);
            for (int g = 0; g < GS; g++) { float ls = lgg[g] - lse; ent -= expf(ls) * ls; }
            lp += lgg[left_config[t]] - lse;
        }
    }
    if (tid == 0) { ws[WS_PE + t] = ent; ws[WS_PL + t] = lp; }
}

__global__ void k_reduce(const float* __restrict__ ws, float* __restrict__ out) {
    const int tid = threadIdx.x;   // 128 threads, 2 waves
    __shared__ float s4[4];
    float e = ws[WS_PE + tid], p = ws[WS_PL + tid];
#pragma unroll
    for (int off = 32; off > 0; off >>= 1) {
        e += __shfl_xor(e, off, 64);
        p += __shfl_xor(p, off, 64);
    }
    if ((tid & 63) == 0) { s4[(tid >> 6) * 2] = e; s4[(tid >> 6) * 2 + 1] = p; }
    __syncthreads();
    if (tid == 0) { out[0] = s4[0] + s4[2]; out[1] = s4[1] + s4[3]; }
}

extern "C" void kernel_launch(void* const* d_in, const int* in_sizes, int n_in,
                              void* d_out, int out_size, void* d_ws, size_t ws_size,
                              hipStream_t stream)
{
    const float* g_emb  = (const float*)d_in[0];
    const float* W_ih   = (const float*)d_in[1];
    const float* W_hh   = (const float*)d_in[2];
    const float* b_ih   = (const float*)d_in[3];
    const float* b_hh   = (const float*)d_in[4];
    const float* ctx_W  = (const float*)d_in[5];
    const float* ctx_b  = (const float*)d_in[6];
    const float* left_W = (const float*)d_in[7];
    const float* left_b = (const float*)d_in[8];
    const int* config      = (const int*)d_in[9];
    const int* left_config = (const int*)d_in[10];
    float* out = (float*)d_out;
    float* ws  = (float*)d_ws;

    k_init<<<dim3(16), dim3(256), 0, stream>>>(ws);
    k_chain<<<dim3(NBLK), dim3(TPB), 0, stream>>>(g_emb, W_ih, W_hh, b_ih, b_hh, config, ws);
    k_heads<<<dim3(AL), dim3(256), 0, stream>>>(ctx_W, ctx_b, left_W, left_b,
                                                config, left_config, ws);
    k_reduce<<<dim3(1), dim3(128), 0, stream>>>(ws, out);
}